// Round 2
// baseline (1167.432 us; speedup 1.0000x reference)
//
#include <hip/hip_runtime.h>
#include <hip/hip_bf16.h>
#include <cstdint>

typedef __attribute__((ext_vector_type(8))) short bf16x8;
typedef __attribute__((ext_vector_type(4))) float f32x4;
typedef __attribute__((ext_vector_type(4))) uint u32x4;

#define LOG2E 1.4426950408889634f
#define SCL2E (0.17677669529663687f * LOG2E)
#define MASKV (-100.0f * LOG2E)

// ---- workspace layout (bytes) ----
#define WTP_OFF   393216   // after WTq: 196608 ushort
#define BIASP_OFF 524288   // after WTp: 65536 ushort; biasP: 8*49*64 floats = 100352 B

// ---- LDS layout (bytes) ----
#define QK_OFF 0          // [64 tok][512 cols] bf16 (cols 0-255 q, 256-511 k), stride 1024 B
#define VT_OFF 65536      // [256 d][64 key] bf16, stride 128 B
#define XS_OFF 98304      // [64 tok][256] bf16 (x staged; reused as attn_out), stride 512 B
#define MF_OFF 131072     // [49 q][64 key] f32 mask-add (incl -1e30 pads), stride 256 B
#define LDS_TOTAL 143616

__device__ __forceinline__ ushort f2bf(float f) {
  uint u = __builtin_bit_cast(uint, f);
  u += 0x7fffu + ((u >> 16) & 1u);
  return (ushort)(u >> 16);
}
__device__ __forceinline__ uint cvtpk(float lo, float hi) {
  uint r; asm("v_cvt_pk_bf16_f32 %0, %1, %2" : "=v"(r) : "v"(lo), "v"(hi)); return r;
}
__device__ __forceinline__ float exp2fast(float x) {
  float r; asm("v_exp_f32 %0, %1" : "=v"(r) : "v"(x)); return r;
}
__device__ __forceinline__ float rcpfast(float x) {
  float r; asm("v_rcp_f32 %0, %1" : "=v"(r) : "v"(x)); return r;
}
// barrier that does NOT drain vmcnt (keeps x/mask prefetch loads in flight);
// lgkmcnt(0) makes all LDS writes/reads of this wave visible before the barrier.
__device__ __forceinline__ void barrier_lds() {
  asm volatile("s_waitcnt lgkmcnt(0)" ::: "memory");
  __builtin_amdgcn_s_barrier();
}

extern "C" __global__ void wattn_prep(const float* __restrict__ qkv_w,
                                      const float* __restrict__ proj_w,
                                      const float* __restrict__ bt,
                                      ushort* __restrict__ WTq,
                                      ushort* __restrict__ WTp,
                                      float* __restrict__ biasP) {
  int id = blockIdx.x * 256 + threadIdx.x;
  if (id < 196608) {                     // WTq[oc][ic] = qkv_w[ic][oc]
    int oc = id >> 8, ic = id & 255;
    WTq[id] = f2bf(qkv_w[ic * 768 + oc]);
  }
  if (id < 65536) {                      // WTp[oc][ic] = proj_w[ic][oc]
    int oc = id >> 8, ic = id & 255;
    WTp[id] = f2bf(proj_w[ic * 256 + oc]);
  }
  if (id < 25088) {                      // biasP[h][q][64 padded keys] * log2e
    int h = id / 3136, r = id % 3136, q = r >> 6, key = r & 63;
    float v = 0.f;
    if (key < 49) {
      int dx = (q % 7) - (key % 7);
      int dy = (q / 7) - (key / 7);
      int idx = 13 * (dx + dy + 12);     // reference formula
      if (idx > 168) idx = 168;          // JAX clamps OOB gather
      v = bt[idx * 8 + h] * LOG2E;
    }
    biasP[id] = v;
  }
}

extern "C" __global__ __launch_bounds__(512, 2)
void wattn_fused(const float* __restrict__ x, const int* __restrict__ mask,
                 const float* __restrict__ qkv_b, const float* __restrict__ proj_b,
                 const ushort* __restrict__ WTq, const ushort* __restrict__ WTp,
                 const float* __restrict__ biasP, float* __restrict__ out) {
  extern __shared__ char lds[];
  const int tid = threadIdx.x;
  const int wid = tid >> 6;    // wave = head
  const int lane = tid & 63;
  const int g = lane >> 4;
  const int c = lane & 15;
  const int h = wid;
  const f32x4 zero4 = {0.f, 0.f, 0.f, 0.f};

  // ---- zero-init QK + VT + XS once (pad rows/cols must stay 0 forever) ----
  {
    uint4 z; z.x = z.y = z.z = z.w = 0;
    for (int i = tid; i < 8192; i += 512) *(uint4*)(lds + i * 16) = z;
  }

  // ---- hoisted per-wave constants ----
  int colbase[6];
  #pragma unroll
  for (int nt = 0; nt < 6; ++nt) colbase[nt] = (nt >> 1) * 256 + h * 32 + (nt & 1) * 16;
  f32x4 bq[6];
  #pragma unroll
  for (int nt = 0; nt < 6; ++nt) bq[nt] = *(const f32x4*)(qkv_b + colbase[nt] + g * 4);
  bq[0] = bq[0] * SCL2E;   // q path: (acc+b)*s == acc*s + b*s
  bq[1] = bq[1] * SCL2E;
  f32x4 pbq[2];
  #pragma unroll
  for (int ot = 0; ot < 2; ++ot) pbq[ot] = *(const f32x4*)(proj_b + h * 32 + ot * 16 + g * 4);

  // ---- prefetch window 0 (x + mask) into registers ----
  float4 px[7]; int pm[7];
  #pragma unroll
  for (int k = 0; k < 7; ++k) { pm[k] = 0; }
  {
    const float* xw = x + (size_t)blockIdx.x * 32 * 12544;
    const int* mw = mask + (size_t)((blockIdx.x * 32) & 1023) * 2401;
    #pragma unroll
    for (int k = 0; k < 7; ++k) {
      int i = tid + k * 512;
      if (i < 3136) {
        px[k] = ((const float4*)xw)[i];
        int km = i & 63;
        if (km < 49) pm[k] = mw[(i >> 6) * 49 + km];
      }
    }
  }
  barrier_lds();

  #pragma unroll 1
  for (int it = 0; it < 32; ++it) {
    const int w = blockIdx.x * 32 + it;

    // ================= Phase 0: x -> XS (bf16), maskF build =================
    #pragma unroll
    for (int k = 0; k < 7; ++k) {
      int i = tid + k * 512;
      if (i < 3136) {
        int row = i >> 6;
        uint off = (uint)(XS_OFF + row * 512 + (i & 63) * 8) ^ (((uint)row & 7) << 4);
        uint2 u; u.x = cvtpk(px[k].x, px[k].y); u.y = cvtpk(px[k].z, px[k].w);
        *(uint2*)(lds + off) = u;
        int km = i & 63;
        float mv = (km < 49) ? ((pm[k] != 0) ? MASKV : 0.f) : -1e30f;
        *(float*)(lds + ((uint)(MF_OFF + row * 256 + km * 4) ^ (((uint)row & 7) << 4))) = mv;
      }
    }
    // issue prefetch for next window (stays in flight across barriers)
    if (it < 31) {
      const float* xn = x + (size_t)(w + 1) * 12544;
      const int* mn = mask + (size_t)((w + 1) & 1023) * 2401;
      #pragma unroll
      for (int k = 0; k < 7; ++k) {
        int i = tid + k * 512;
        if (i < 3136) {
          px[k] = ((const float4*)xn)[i];
          int km = i & 63;
          if (km < 49) pm[k] = mn[(i >> 6) * 49 + km];
        }
      }
    }
    barrier_lds();

    // ================= Phase 1: qkv^T = W^T x^T (swapped) =================
    {
      f32x4 acc[6][4];
      #pragma unroll
      for (int nt = 0; nt < 6; ++nt)
        #pragma unroll
        for (int tt = 0; tt < 4; ++tt) acc[nt][tt] = zero4;

      #pragma unroll 1
      for (int ks = 0; ks < 8; ++ks) {
        bf16x8 wa[6];
        #pragma unroll
        for (int nt = 0; nt < 6; ++nt)
          wa[nt] = *(const bf16x8*)(WTq + (size_t)(colbase[nt] + c) * 256 + ks * 32 + g * 8);
        bf16x8 bx[4];
        #pragma unroll
        for (int tt = 0; tt < 4; ++tt) {
          uint off = (uint)(XS_OFF + (tt * 16 + c) * 512 + (ks * 32 + g * 8) * 2) ^ (((uint)c & 7) << 4);
          bx[tt] = *(const bf16x8*)(lds + off);
        }
        #pragma unroll
        for (int nt = 0; nt < 6; ++nt)
          #pragma unroll
          for (int tt = 0; tt < 4; ++tt)
            acc[nt][tt] = __builtin_amdgcn_mfma_f32_16x16x32_bf16(wa[nt], bx[tt], acc[nt][tt], 0, 0, 0);
      }
      // epilogue: lane holds token=tt*16+c, 4 consecutive out-dims (g*4+r)
      #pragma unroll
      for (int tt = 0; tt < 4; ++tt) {
        int tok = tt * 16 + c;
        if (tok < 49) {
          uint swz = ((uint)tok & 7) << 4;
          #pragma unroll
          for (int nt = 0; nt < 2; ++nt) {  // q (scaled, exp2 domain)
            f32x4 v = acc[nt][tt] * SCL2E + bq[nt];
            uint2 u; u.x = cvtpk(v[0], v[1]); u.y = cvtpk(v[2], v[3]);
            *(uint2*)(lds + ((uint)(QK_OFF + tok * 1024 + (h * 32 + nt * 16 + g * 4) * 2) ^ swz)) = u;
          }
          #pragma unroll
          for (int nt = 2; nt < 4; ++nt) {  // k
            f32x4 v = acc[nt][tt] + bq[nt];
            uint2 u; u.x = cvtpk(v[0], v[1]); u.y = cvtpk(v[2], v[3]);
            *(uint2*)(lds + ((uint)(QK_OFF + tok * 1024 + (256 + h * 32 + (nt - 2) * 16 + g * 4) * 2) ^ swz)) = u;
          }
          #pragma unroll
          for (int nt = 4; nt < 6; ++nt) {  // v -> VT[d][tok] (transposed, scalar)
            f32x4 v = acc[nt][tt] + bq[nt];
            int d0 = h * 32 + (nt - 4) * 16 + g * 4;
            #pragma unroll
            for (int r = 0; r < 4; ++r) {
              int d = d0 + r;
              *(ushort*)(lds + ((uint)(VT_OFF + d * 128 + tok * 2) ^ (((uint)d & 7) << 4))) = f2bf(v[r]);
            }
          }
        }
      }
    }
    barrier_lds();

    // ================= Phase 2: attention (all in-register P) =================
    {
      // hoisted A-frags: k rows (permuted key map) and V^T rows
      bf16x8 ka[4], va[2][2];
      #pragma unroll
      for (int kt = 0; kt < 4; ++kt) {
        int krow = ((c >> 2) << 3) + ((kt & 1) << 2) + (c & 3) + ((kt >> 1) << 5);
        uint off = (uint)(QK_OFF + krow * 1024 + (256 + h * 32 + g * 8) * 2) ^ (((uint)krow & 7) << 4);
        ka[kt] = *(const bf16x8*)(lds + off);
      }
      #pragma unroll
      for (int dt = 0; dt < 2; ++dt)
        #pragma unroll
        for (int ks = 0; ks < 2; ++ks) {
          int d = h * 32 + dt * 16 + c;
          uint off = (uint)(VT_OFF + d * 128 + (ks * 32 + g * 8) * 2) ^ (((uint)d & 7) << 4);
          va[dt][ks] = *(const bf16x8*)(lds + off);
        }

      #pragma unroll 1
      for (int qt = 0; qt < 4; ++qt) {
        int q = qt * 16 + c;
        uint qoff = (uint)(QK_OFF + q * 1024 + (h * 32 + g * 8) * 2) ^ (((uint)q & 7) << 4);
        bf16x8 bqf = *(const bf16x8*)(lds + qoff);
        f32x4 s[4];
        #pragma unroll
        for (int kt = 0; kt < 4; ++kt)
          s[kt] = __builtin_amdgcn_mfma_f32_16x16x32_bf16(ka[kt], bqf, zero4, 0, 0, 0);
        int qc = (q < 49) ? q : 48;
        #pragma unroll
        for (int kt = 0; kt < 4; ++kt) {
          int kb = g * 8 + ((kt & 1) << 2) + ((kt >> 1) << 5);  // key base (4 consecutive)
          f32x4 b4 = *(const f32x4*)(biasP + (h * 49 + qc) * 64 + kb);
          f32x4 m4 = *(const f32x4*)(lds + ((uint)(MF_OFF + qc * 256 + kb * 4) ^ (((uint)qc & 7) << 4)));
          s[kt] = s[kt] + b4 + m4;
        }
        // softmax over 64 keys: 16 in-lane + cross-group (g) reduce
        float mx = s[0][0];
        #pragma unroll
        for (int kt = 0; kt < 4; ++kt)
          #pragma unroll
          for (int r = 0; r < 4; ++r) mx = fmaxf(mx, s[kt][r]);
        mx = fmaxf(mx, __shfl_xor(mx, 16));
        mx = fmaxf(mx, __shfl_xor(mx, 32));
        float sum = 0.f;
        #pragma unroll
        for (int kt = 0; kt < 4; ++kt)
          #pragma unroll
          for (int r = 0; r < 4; ++r) {
            float e = exp2fast(s[kt][r] - mx);
            s[kt][r] = e;
            sum += e;
          }
        sum += __shfl_xor(sum, 16);
        sum += __shfl_xor(sum, 32);
        float rdn = rcpfast(sum);
        // pack P fragments fully in-register (key map makes them lane-local)
        u32x4 w0 = {cvtpk(s[0][0], s[0][1]), cvtpk(s[0][2], s[0][3]),
                    cvtpk(s[1][0], s[1][1]), cvtpk(s[1][2], s[1][3])};
        u32x4 w1 = {cvtpk(s[2][0], s[2][1]), cvtpk(s[2][2], s[2][3]),
                    cvtpk(s[3][0], s[3][1]), cvtpk(s[3][2], s[3][3])};
        bf16x8 pb0 = __builtin_bit_cast(bf16x8, w0);
        bf16x8 pb1 = __builtin_bit_cast(bf16x8, w1);
        // PV: O^T[d][q]
        f32x4 o0 = __builtin_amdgcn_mfma_f32_16x16x32_bf16(va[0][0], pb0, zero4, 0, 0, 0);
        o0 = __builtin_amdgcn_mfma_f32_16x16x32_bf16(va[0][1], pb1, o0, 0, 0, 0);
        f32x4 o1 = __builtin_amdgcn_mfma_f32_16x16x32_bf16(va[1][0], pb0, zero4, 0, 0, 0);
        o1 = __builtin_amdgcn_mfma_f32_16x16x32_bf16(va[1][1], pb1, o1, 0, 0, 0);
        if (q < 49) {
          uint swz = ((uint)q & 7) << 4;
          f32x4 v0 = o0 * rdn, v1 = o1 * rdn;
          uint2 u0; u0.x = cvtpk(v0[0], v0[1]); u0.y = cvtpk(v0[2], v0[3]);
          uint2 u1; u1.x = cvtpk(v1[0], v1[1]); u1.y = cvtpk(v1[2], v1[3]);
          *(uint2*)(lds + ((uint)(XS_OFF + q * 512 + (h * 32 + g * 4) * 2) ^ swz)) = u0;
          *(uint2*)(lds + ((uint)(XS_OFF + q * 512 + (h * 32 + 16 + g * 4) * 2) ^ swz)) = u1;
        }
      }
    }
    barrier_lds();

    // ================= Phase 3: out^T = Wp^T attn^T (swapped) =================
    {
      f32x4 pacc[2][4];
      #pragma unroll
      for (int ot = 0; ot < 2; ++ot)
        #pragma unroll
        for (int tt = 0; tt < 4; ++tt) pacc[ot][tt] = zero4;

      #pragma unroll 1
      for (int ks = 0; ks < 8; ++ks) {
        bf16x8 wp[2];
        #pragma unroll
        for (int ot = 0; ot < 2; ++ot)
          wp[ot] = *(const bf16x8*)(WTp + (size_t)(h * 32 + ot * 16 + c) * 256 + ks * 32 + g * 8);
        bf16x8 bx[4];
        #pragma unroll
        for (int tt = 0; tt < 4; ++tt) {
          uint off = (uint)(XS_OFF + (tt * 16 + c) * 512 + (ks * 32 + g * 8) * 2) ^ (((uint)c & 7) << 4);
          bx[tt] = *(const bf16x8*)(lds + off);
        }
        #pragma unroll
        for (int ot = 0; ot < 2; ++ot)
          #pragma unroll
          for (int tt = 0; tt < 4; ++tt)
            pacc[ot][tt] = __builtin_amdgcn_mfma_f32_16x16x32_bf16(wp[ot], bx[tt], pacc[ot][tt], 0, 0, 0);
      }
      float* ob = out + (size_t)w * 12544;
      #pragma unroll
      for (int ot = 0; ot < 2; ++ot)
        #pragma unroll
        for (int tt = 0; tt < 4; ++tt) {
          int tok = tt * 16 + c;
          if (tok < 49) {
            f32x4 r = pacc[ot][tt] + pbq[ot];
            *(f32x4*)(ob + tok * 256 + h * 32 + ot * 16 + g * 4) = r;
          }
        }
    }
    barrier_lds();   // XS free before next window's phase 0
  }
}

extern "C" void kernel_launch(void* const* d_in, const int* in_sizes, int n_in,
                              void* d_out, int out_size, void* d_ws, size_t ws_size,
                              hipStream_t stream) {
  const float* x      = (const float*)d_in[0];
  const int*   mask   = (const int*)d_in[1];
  const float* qkv_w  = (const float*)d_in[2];
  const float* qkv_b  = (const float*)d_in[3];
  const float* proj_w = (const float*)d_in[4];
  const float* proj_b = (const float*)d_in[5];
  const float* bt     = (const float*)d_in[6];
  float* out = (float*)d_out;

  ushort* WTq   = (ushort*)d_ws;
  ushort* WTp   = (ushort*)((char*)d_ws + WTP_OFF);
  float*  biasP = (float*)((char*)d_ws + BIASP_OFF);

  hipLaunchKernelGGL(wattn_prep, dim3(768), dim3(256), 0, stream,
                     qkv_w, proj_w, bt, WTq, WTp, biasP);

  hipFuncSetAttribute(reinterpret_cast<const void*>(wattn_fused),
                      hipFuncAttributeMaxDynamicSharedMemorySize, LDS_TOTAL);
  hipLaunchKernelGGL(wattn_fused, dim3(256), dim3(512), LDS_TOTAL, stream,
                     x, mask, qkv_b, proj_b, WTq, WTp, biasP, out);
}

// Round 3
// 718.704 us; speedup vs baseline: 1.6244x; 1.6244x over previous
//
#include <hip/hip_runtime.h>
#include <hip/hip_bf16.h>
#include <cstdint>

typedef __attribute__((ext_vector_type(8))) short bf16x8;
typedef __attribute__((ext_vector_type(4))) float f32x4;
typedef __attribute__((ext_vector_type(4))) uint u32x4;

#define LOG2E 1.4426950408889634f
#define SCL2E (0.17677669529663687f * LOG2E)

// ---- workspace layout (bytes) ----
#define WTP_OFF   393216   // after WTq: 196608 ushort
#define BIASP_OFF 524288   // after WTp: 65536 ushort; biasP: 8*49*64 f32

// ---- LDS layout (bytes), total < 80 KiB => 2 blocks/CU ----
#define XQ_OFF 0        // [50][256] bf16, stride 512 B: x -> q -> attn_out (XOR swizzled)
#define K_OFF  25600    // [50][256] bf16, stride 512 B: k (XOR swizzled)
#define VT_OFF 51200    // [256 d][56 tok] bf16, stride 112 B (no swizzle) + 16 B zero tail
#define M64_OFF 79888   // 49 x uint64 mask bitmasks
#define LDS_TOTAL 80384

__device__ __forceinline__ ushort f2bf(float f) {
  uint u = __builtin_bit_cast(uint, f);
  u += 0x7fffu + ((u >> 16) & 1u);
  return (ushort)(u >> 16);
}
__device__ __forceinline__ uint cvtpk(float lo, float hi) {
  uint r; asm("v_cvt_pk_bf16_f32 %0, %1, %2" : "=v"(r) : "v"(lo), "v"(hi)); return r;
}
__device__ __forceinline__ float exp2fast(float x) {
  float r; asm("v_exp_f32 %0, %1" : "=v"(r) : "v"(x)); return r;
}
__device__ __forceinline__ float rcpfast(float x) {
  float r; asm("v_rcp_f32 %0, %1" : "=v"(r) : "v"(x)); return r;
}

extern "C" __global__ void wattn_prep(const float* __restrict__ qkv_w,
                                      const float* __restrict__ proj_w,
                                      const float* __restrict__ bt,
                                      ushort* __restrict__ WTq,
                                      ushort* __restrict__ WTp,
                                      float* __restrict__ biasP) {
  int id = blockIdx.x * 256 + threadIdx.x;
  if (id < 196608) {                     // WTq[oc][ic] = qkv_w[ic][oc]
    int oc = id >> 8, ic = id & 255;
    WTq[id] = f2bf(qkv_w[ic * 768 + oc]);
  }
  if (id < 65536) {                      // WTp[oc][ic] = proj_w[ic][oc]
    int oc = id >> 8, ic = id & 255;
    WTp[id] = f2bf(proj_w[ic * 256 + oc]);
  }
  if (id < 25088) {                      // biasP[h][q][64 padded keys] * log2e
    int h = id / 3136, r = id % 3136, q = r >> 6, key = r & 63;
    float v = 0.f;
    if (key < 49) {
      int dx = (q % 7) - (key % 7);
      int dy = (q / 7) - (key / 7);
      int idx = 13 * (dx + dy + 12);     // reference formula
      if (idx > 168) idx = 168;          // JAX clamps OOB gather
      v = bt[idx * 8 + h] * LOG2E;
    }
    biasP[id] = v;
  }
}

extern "C" __global__ __launch_bounds__(512, 4)
void wattn_fused(const float* __restrict__ x, const int* __restrict__ mask,
                 const float* __restrict__ qkv_b, const float* __restrict__ proj_b,
                 const ushort* __restrict__ WTq, const ushort* __restrict__ WTp,
                 const float* __restrict__ biasP, float* __restrict__ out) {
  extern __shared__ char lds[];
  const int tid = threadIdx.x;
  const int wid = tid >> 6;    // wave = head
  const int lane = tid & 63;
  const int g = lane >> 4;
  const int c = lane & 15;
  const int h = wid;
  const int w = blockIdx.x;
  const f32x4 zero4 = {0.f, 0.f, 0.f, 0.f};

  // ================= Phase 0: init pads, stage x, build mask bitmasks =================
  {
    uint4 z; z.x = z.y = z.z = z.w = 0;
    // VT region + 16B tail: 28688 B = 1793 uint4
    for (int i = tid; i < 1793; i += 512) *(uint4*)(lds + VT_OFF + i * 16) = z;
    // XQ row 49 and K row 49 (512 B each)
    if (tid < 32) *(uint4*)(lds + XQ_OFF + 49 * 512 + tid * 16) = z;
    else if (tid < 64) *(uint4*)(lds + K_OFF + 49 * 512 + (tid - 32) * 16) = z;

    const float4* xb = (const float4*)(x + (size_t)w * 12544);
    #pragma unroll 2
    for (int i = tid; i < 3136; i += 512) {
      float4 v = xb[i];
      int r = i >> 6;
      uint off = (uint)(XQ_OFF + r * 512 + (i & 63) * 8) ^ (((uint)r & 7) << 4);
      uint2 u; u.x = cvtpk(v.x, v.y); u.y = cvtpk(v.z, v.w);
      *(uint2*)(lds + off) = u;
    }
    const int* mrow = mask + (size_t)(w & 1023) * 2401;
    for (int r = wid; r < 49; r += 8) {
      int mv = (lane < 49) ? mrow[r * 49 + lane] : 0;
      unsigned long long bal = __ballot(mv != 0);
      if (lane == 0) *(unsigned long long*)(lds + M64_OFF + r * 8) = bal;
    }
  }
  __syncthreads();

  // ================= Phase 1a: k,v = W_kv^T x^T (swapped operands) =================
  {
    f32x4 acc[4][4];
    #pragma unroll
    for (int j = 0; j < 4; ++j)
      #pragma unroll
      for (int tt = 0; tt < 4; ++tt) acc[j][tt] = zero4;

    #pragma unroll 1
    for (int ks = 0; ks < 8; ++ks) {
      bf16x8 bx[4];
      #pragma unroll
      for (int tt = 0; tt < 4; ++tt) {
        int row = tt * 16 + c; if (row > 49) row = 49;
        uint off = (uint)(XQ_OFF + row * 512 + (ks * 32 + g * 8) * 2) ^ (((uint)row & 7) << 4);
        bx[tt] = *(const bf16x8*)(lds + off);
      }
      #pragma unroll
      for (int j = 0; j < 4; ++j) {
        int oc = (j < 2) ? (256 + h * 32 + j * 16) : (512 + h * 32 + (j - 2) * 16);
        bf16x8 wa = *(const bf16x8*)(WTq + (size_t)(oc + c) * 256 + ks * 32 + g * 8);
        #pragma unroll
        for (int tt = 0; tt < 4; ++tt)
          acc[j][tt] = __builtin_amdgcn_mfma_f32_16x16x32_bf16(wa, bx[tt], acc[j][tt], 0, 0, 0);
      }
    }
    // epilogue: k -> K region (vectorized), v -> VT (transposed, scalar)
    f32x4 bk[2], bv[2];
    #pragma unroll
    for (int j = 0; j < 2; ++j) {
      bk[j] = *(const f32x4*)(qkv_b + 256 + h * 32 + j * 16 + g * 4);
      bv[j] = *(const f32x4*)(qkv_b + 512 + h * 32 + j * 16 + g * 4);
    }
    #pragma unroll
    for (int tt = 0; tt < 4; ++tt) {
      int tok = tt * 16 + c;
      if (tok < 49) {
        uint swz = ((uint)tok & 7) << 4;
        #pragma unroll
        for (int j = 0; j < 2; ++j) {
          f32x4 v = acc[j][tt] + bk[j];
          uint2 u; u.x = cvtpk(v[0], v[1]); u.y = cvtpk(v[2], v[3]);
          *(uint2*)(lds + ((uint)(K_OFF + tok * 512 + (h * 32 + j * 16 + g * 4) * 2) ^ swz)) = u;
        }
        #pragma unroll
        for (int j = 0; j < 2; ++j) {
          f32x4 v = acc[j + 2][tt] + bv[j];
          int d0 = h * 32 + j * 16 + g * 4;
          #pragma unroll
          for (int r = 0; r < 4; ++r)
            *(ushort*)(lds + VT_OFF + (d0 + r) * 112 + tok * 2) = f2bf(v[r]);
        }
      }
    }
  }

  // ================= Phase 1b: q = W_q^T x^T, then overwrite x with q =================
  {
    f32x4 acc[2][4];
    #pragma unroll
    for (int j = 0; j < 2; ++j)
      #pragma unroll
      for (int tt = 0; tt < 4; ++tt) acc[j][tt] = zero4;

    #pragma unroll 1
    for (int ks = 0; ks < 8; ++ks) {
      bf16x8 bx[4];
      #pragma unroll
      for (int tt = 0; tt < 4; ++tt) {
        int row = tt * 16 + c; if (row > 49) row = 49;
        uint off = (uint)(XQ_OFF + row * 512 + (ks * 32 + g * 8) * 2) ^ (((uint)row & 7) << 4);
        bx[tt] = *(const bf16x8*)(lds + off);
      }
      #pragma unroll
      for (int j = 0; j < 2; ++j) {
        bf16x8 wa = *(const bf16x8*)(WTq + (size_t)(h * 32 + j * 16 + c) * 256 + ks * 32 + g * 8);
        #pragma unroll
        for (int tt = 0; tt < 4; ++tt)
          acc[j][tt] = __builtin_amdgcn_mfma_f32_16x16x32_bf16(wa, bx[tt], acc[j][tt], 0, 0, 0);
      }
    }
    __syncthreads();   // all waves done reading x before q overwrites it
    f32x4 bqv[2];
    #pragma unroll
    for (int j = 0; j < 2; ++j)
      bqv[j] = *(const f32x4*)(qkv_b + h * 32 + j * 16 + g * 4) * SCL2E;
    #pragma unroll
    for (int tt = 0; tt < 4; ++tt) {
      int tok = tt * 16 + c;
      if (tok < 49) {
        uint swz = ((uint)tok & 7) << 4;
        #pragma unroll
        for (int j = 0; j < 2; ++j) {
          f32x4 v = acc[j][tt] * SCL2E + bqv[j];
          uint2 u; u.x = cvtpk(v[0], v[1]); u.y = cvtpk(v[2], v[3]);
          *(uint2*)(lds + ((uint)(XQ_OFF + tok * 512 + (h * 32 + j * 16 + g * 4) * 2) ^ swz)) = u;
        }
      }
    }
  }
  __syncthreads();

  // ================= Phase 2: attention (in-register P, exp2 softmax) =================
  {
    bf16x8 ka[4], va[2][2];
    #pragma unroll
    for (int kt = 0; kt < 4; ++kt) {
      int krow = ((c >> 2) << 3) + ((kt & 1) << 2) + (c & 3) + ((kt >> 1) << 5);
      if (krow > 49) krow = 49;
      uint off = (uint)(K_OFF + krow * 512 + (h * 32 + g * 8) * 2) ^ (((uint)krow & 7) << 4);
      ka[kt] = *(const bf16x8*)(lds + off);
    }
    #pragma unroll
    for (int dt = 0; dt < 2; ++dt)
      #pragma unroll
      for (int ks = 0; ks < 2; ++ks) {
        int d = h * 32 + dt * 16 + c;
        va[dt][ks] = *(const bf16x8*)(lds + VT_OFF + d * 112 + (ks * 32 + g * 8) * 2);
      }

    #pragma unroll 1
    for (int qt = 0; qt < 4; ++qt) {
      int q = qt * 16 + c;
      int qc = (q < 49) ? q : 48;
      int qrow = (q < 49) ? q : 49;
      // issue loads first
      uint2 m2 = *(const uint2*)(lds + M64_OFF + qc * 8);
      unsigned long long m64 =
          (unsigned long long)m2.x | ((unsigned long long)(m2.y | 0xFFFE0000u) << 32);
      int kb[4];
      f32x4 b4[4];
      #pragma unroll
      for (int kt = 0; kt < 4; ++kt) {
        kb[kt] = g * 8 + ((kt & 1) << 2) + ((kt >> 1) << 5);
        b4[kt] = *(const f32x4*)(biasP + (size_t)(h * 49 + qc) * 64 + kb[kt]);
      }
      uint qoff = (uint)(XQ_OFF + qrow * 512 + (h * 32 + g * 8) * 2) ^ (((uint)qrow & 7) << 4);
      bf16x8 bqf = *(const bf16x8*)(lds + qoff);
      f32x4 s[4];
      #pragma unroll
      for (int kt = 0; kt < 4; ++kt)
        s[kt] = __builtin_amdgcn_mfma_f32_16x16x32_bf16(ka[kt], bqf, zero4, 0, 0, 0);
      #pragma unroll
      for (int kt = 0; kt < 4; ++kt) s[kt] = s[kt] + b4[kt];
      // max over 64 keys (pads contribute s=0: harmless consistent rescale)
      float mx = s[0][0];
      #pragma unroll
      for (int kt = 0; kt < 4; ++kt)
        #pragma unroll
        for (int r = 0; r < 4; ++r) mx = fmaxf(mx, s[kt][r]);
      mx = fmaxf(mx, __shfl_xor(mx, 16));
      mx = fmaxf(mx, __shfl_xor(mx, 32));
      float sum = 0.f;
      #pragma unroll
      for (int kt = 0; kt < 4; ++kt) {
        uint nib = (uint)(m64 >> kb[kt]) & 0xFu;
        #pragma unroll
        for (int r = 0; r < 4; ++r) {
          float e = exp2fast(s[kt][r] - mx);
          e = ((nib >> r) & 1u) ? 0.f : e;   // masked / pad keys -> 0 weight
          s[kt][r] = e;
          sum += e;
        }
      }
      sum += __shfl_xor(sum, 16);
      sum += __shfl_xor(sum, 32);
      float rdn = rcpfast(sum + 1e-30f);
      // pack P fragments in-register (key map makes them lane-local)
      u32x4 w0 = {cvtpk(s[0][0], s[0][1]), cvtpk(s[0][2], s[0][3]),
                  cvtpk(s[1][0], s[1][1]), cvtpk(s[1][2], s[1][3])};
      u32x4 w1 = {cvtpk(s[2][0], s[2][1]), cvtpk(s[2][2], s[2][3]),
                  cvtpk(s[3][0], s[3][1]), cvtpk(s[3][2], s[3][3])};
      bf16x8 pb0 = __builtin_bit_cast(bf16x8, w0);
      bf16x8 pb1 = __builtin_bit_cast(bf16x8, w1);
      f32x4 o0 = __builtin_amdgcn_mfma_f32_16x16x32_bf16(va[0][0], pb0, zero4, 0, 0, 0);
      o0 = __builtin_amdgcn_mfma_f32_16x16x32_bf16(va[0][1], pb1, o0, 0, 0, 0);
      f32x4 o1 = __builtin_amdgcn_mfma_f32_16x16x32_bf16(va[1][0], pb0, zero4, 0, 0, 0);
      o1 = __builtin_amdgcn_mfma_f32_16x16x32_bf16(va[1][1], pb1, o1, 0, 0, 0);
      if (q < 49) {
        uint swz = ((uint)q & 7) << 4;
        f32x4 v0 = o0 * rdn, v1 = o1 * rdn;
        uint2 u0; u0.x = cvtpk(v0[0], v0[1]); u0.y = cvtpk(v0[2], v0[3]);
        uint2 u1; u1.x = cvtpk(v1[0], v1[1]); u1.y = cvtpk(v1[2], v1[3]);
        *(uint2*)(lds + ((uint)(XQ_OFF + q * 512 + (h * 32 + g * 4) * 2) ^ swz)) = u0;
        *(uint2*)(lds + ((uint)(XQ_OFF + q * 512 + (h * 32 + 16 + g * 4) * 2) ^ swz)) = u1;
      }
    }
  }
  __syncthreads();

  // ================= Phase 3: out^T = Wp^T attn^T =================
  {
    f32x4 pacc[2][4];
    #pragma unroll
    for (int ot = 0; ot < 2; ++ot)
      #pragma unroll
      for (int tt = 0; tt < 4; ++tt) pacc[ot][tt] = zero4;

    #pragma unroll 1
    for (int ks = 0; ks < 8; ++ks) {
      bf16x8 bx[4];
      #pragma unroll
      for (int tt = 0; tt < 4; ++tt) {
        int row = tt * 16 + c; if (row > 49) row = 49;
        uint off = (uint)(XQ_OFF + row * 512 + (ks * 32 + g * 8) * 2) ^ (((uint)row & 7) << 4);
        bx[tt] = *(const bf16x8*)(lds + off);
      }
      #pragma unroll
      for (int ot = 0; ot < 2; ++ot) {
        bf16x8 wp = *(const bf16x8*)(WTp + (size_t)(h * 32 + ot * 16 + c) * 256 + ks * 32 + g * 8);
        #pragma unroll
        for (int tt = 0; tt < 4; ++tt)
          pacc[ot][tt] = __builtin_amdgcn_mfma_f32_16x16x32_bf16(wp, bx[tt], pacc[ot][tt], 0, 0, 0);
      }
    }
    float* ob = out + (size_t)w * 12544;
    #pragma unroll
    for (int ot = 0; ot < 2; ++ot) {
      f32x4 pb = *(const f32x4*)(proj_b + h * 32 + ot * 16 + g * 4);
      #pragma unroll
      for (int tt = 0; tt < 4; ++tt) {
        int tok = tt * 16 + c;
        if (tok < 49) {
          f32x4 r = pacc[ot][tt] + pb;
          *(f32x4*)(ob + tok * 256 + h * 32 + ot * 16 + g * 4) = r;
        }
      }
    }
  }
}

extern "C" void kernel_launch(void* const* d_in, const int* in_sizes, int n_in,
                              void* d_out, int out_size, void* d_ws, size_t ws_size,
                              hipStream_t stream) {
  const float* x      = (const float*)d_in[0];
  const int*   mask   = (const int*)d_in[1];
  const float* qkv_w  = (const float*)d_in[2];
  const float* qkv_b  = (const float*)d_in[3];
  const float* proj_w = (const float*)d_in[4];
  const float* proj_b = (const float*)d_in[5];
  const float* bt     = (const float*)d_in[6];
  float* out = (float*)d_out;

  ushort* WTq   = (ushort*)d_ws;
  ushort* WTp   = (ushort*)((char*)d_ws + WTP_OFF);
  float*  biasP = (float*)((char*)d_ws + BIASP_OFF);

  hipLaunchKernelGGL(wattn_prep, dim3(768), dim3(256), 0, stream,
                     qkv_w, proj_w, bt, WTq, WTp, biasP);

  hipFuncSetAttribute(reinterpret_cast<const void*>(wattn_fused),
                      hipFuncAttributeMaxDynamicSharedMemorySize, LDS_TOTAL);
  hipLaunchKernelGGL(wattn_fused, dim3(8192), dim3(512), LDS_TOTAL, stream,
                     x, mask, qkv_b, proj_b, WTq, WTp, biasP, out);
}